// Round 6
// baseline (154.973 us; speedup 1.0000x reference)
//
#include <hip/hip_runtime.h>
#include <hip/hip_bf16.h>

// GCN fused pipeline for MI355X (gfx950). All float I/O is FLOAT32.
//
// Algebra: y[b,n] = reg_b[b] + sum_e val_e * z[col_e, b]
//   z[n,b]  = relu( (A@X)[n,:] @ W0[b] ) . v1[b,:]
//   v1[b,h] = sum_c W1[b,h,c] * reg_w[b,c]
// Uses A@(X@W) == (A@X)@W to aggregate on 128 feats instead of 512,
// and linearity of layer2+head to delete GEMM2/SPMM2 entirely.
// bf16 only as internal compression for the MFMA GEMM operands.
//
// Round 6: 5 nodes -> 4. k_spmm and k_gemm fused: 64-row tiles aggregated
// straight into LDS (swizzled), then 8 waves do (batch x col-half) 64x64
// MFMA gemms with B streamed from L2-hot w0t. xa global round-trip deleted.
// deg zeroing -> 80KB memset node; rest of pre fused into the scatter kernel.

#define NN 20000
#define EE 320000
#define BB 4
#define FF 128
#define HH 128
#define CC 64

typedef unsigned short u16;
typedef short short8 __attribute__((ext_vector_type(8)));
typedef float floatx4 __attribute__((ext_vector_type(4)));

static __device__ __forceinline__ float b2f(u16 u) {
    union { unsigned int i; float f; } x;
    x.i = ((unsigned int)u) << 16;
    return x.f;
}

static __device__ __forceinline__ u16 f2b(float f) {
    __hip_bfloat16 h = __float2bfloat16(f);
    return *reinterpret_cast<u16*>(&h);
}

// ---- init: ELL scatter + x->bf16 + W0^T bf16 + v1 (deg pre-zeroed) ---------

__global__ void k_init(const int* __restrict__ rows, const int* __restrict__ cols,
                       const float* __restrict__ vals, int* __restrict__ deg,
                       uint2* __restrict__ epack,
                       const float* __restrict__ x, u16* __restrict__ xb,
                       const float* __restrict__ w0, const float* __restrict__ w1,
                       const float* __restrict__ regw, u16* __restrict__ w0t,
                       float* __restrict__ v1) {
    int gid = blockIdx.x * 256 + threadIdx.x;
    if (gid < EE) {
        int r = rows[gid];
        int p = atomicAdd(&deg[r], 1);
        epack[(r << 6) + p] = make_uint2((unsigned)cols[gid], __float_as_uint(vals[gid]));
    }
    if (gid < NN * FF / 4) {
        float4 v = ((const float4*)x)[gid];
        ushort4 o;
        o.x = f2b(v.x); o.y = f2b(v.y); o.z = f2b(v.z); o.w = f2b(v.w);
        ((ushort4*)xb)[gid] = o;
    }
    if (gid < BB * FF * HH) {
        int b = gid >> 14;
        int rem = gid & 16383;
        int h = rem >> 7;
        int k = rem & 127;
        w0t[gid] = f2b(w0[(b << 14) + (k << 7) + h]);   // w0t[b][h][k] = w0[b][k][h]
    }
    if (gid < BB * HH) {
        int b = gid >> 7;
        int h = gid & 127;
        const float* wrow = w1 + (b * HH + h) * CC;
        const float* rw = regw + b * CC;
        float s = 0.f;
#pragma unroll
        for (int c = 0; c < CC; ++c) s += wrow[c] * rw[c];
        v1[gid] = s;
    }
}

// ---- fused SpMM + GEMM -----------------------------------------------------
// Block = 64-row tile, 512 threads (8 waves).
// Phase A: each wave aggregates 8 rows (8 edges in flight, 16 feats/lane)
//          -> bf16 into LDS sA with XOR-swizzled 16B slots (T2/G4).
// Phase B: wave (b = wv>>1, wc = wv&1) computes 64 rows x 64 cols for batch b
//          via 16x16x32 MFMA, A from LDS, B streamed from L2-hot w0t.
// Epilogue: relu * v1, reduce over cols -> z[n][4].

__global__ __launch_bounds__(512) void k_spmm_gemm(const int* __restrict__ deg,
                                                   const uint2* __restrict__ epack,
                                                   const u16* __restrict__ xb,
                                                   const u16* __restrict__ w0t,
                                                   const float* __restrict__ v1,
                                                   float* __restrict__ z) {
    __shared__ u16 sA[64 * 128];          // 16 KB
    __shared__ float part[BB][2][64];     // 2 KB

    int base = blockIdx.x * 64;
    int t = threadIdx.x;
    int wv = t >> 6;
    int lane = t & 63;

    // ---- Phase A: aggregate rows base..base+63 into sA ----
    {
        int eg = lane >> 3;       // edge slot within group of 8
        int fl = lane & 7;        // feature block: 16 feats = 32B
#pragma unroll
        for (int it = 0; it < 8; ++it) {
            int lr0 = wv * 8 + it;            // local row 0..63
            int row = base + lr0;
            int d = (row < NN) ? deg[row] : 0;
            float acc[16];
#pragma unroll
            for (int j = 0; j < 16; ++j) acc[j] = 0.f;
            int p0 = row << 6;
            for (int p = eg; p < d; p += 8) {
                uint2 ep = epack[p0 + p];
                float v = __uint_as_float(ep.y);
                const u16* xr = xb + (((size_t)ep.x) << 7) + fl * 16;
                short8 x0 = *(const short8*)(xr);
                short8 x1 = *(const short8*)(xr + 8);
#pragma unroll
                for (int j = 0; j < 8; ++j) {
                    acc[j]     += v * b2f((u16)x0[j]);
                    acc[8 + j] += v * b2f((u16)x1[j]);
                }
            }
#pragma unroll
            for (int j = 0; j < 16; ++j) {
                acc[j] += __shfl_xor(acc[j], 8);
                acc[j] += __shfl_xor(acc[j], 16);
                acc[j] += __shfl_xor(acc[j], 32);
            }
            if (eg == 0) {
                short8 o0, o1;
#pragma unroll
                for (int j = 0; j < 8; ++j) {
                    o0[j] = (short)f2b(acc[j]);
                    o1[j] = (short)f2b(acc[8 + j]);
                }
                int c0 = 2 * fl, c1 = 2 * fl + 1;
                *(short8*)(&sA[lr0 * 128 + (c0 ^ (lr0 & 7)) * 8]) = o0;
                *(short8*)(&sA[lr0 * 128 + (c1 ^ (lr0 & 7)) * 8]) = o1;
            }
        }
    }
    __syncthreads();

    // ---- Phase B: gemm 64 x 64 per wave (batch b, col half wc) ----
    {
        int b = wv >> 1;
        int wc = wv & 1;
        int g = lane >> 4;
        int lr = lane & 15;

        floatx4 acc[4][4];
#pragma unroll
        for (int i = 0; i < 4; ++i)
#pragma unroll
            for (int j = 0; j < 4; ++j) acc[i][j] = (floatx4){0.f, 0.f, 0.f, 0.f};

#pragma unroll
        for (int kk = 0; kk < 4; ++kk) {          // K = 128, 32 per step
            short8 a[4], bf[4];
#pragma unroll
            for (int i = 0; i < 4; ++i) {
                int row = i * 16 + lr;
                int slot = (kk * 4 + g) ^ (row & 7);
                a[i] = *(const short8*)(&sA[row * 128 + slot * 8]);
            }
#pragma unroll
            for (int j = 0; j < 4; ++j) {
                int h = wc * 64 + j * 16 + lr;
                bf[j] = *(const short8*)(w0t + (((size_t)b) << 14) + (h << 7) + kk * 32 + g * 8);
            }
#pragma unroll
            for (int i = 0; i < 4; ++i)
#pragma unroll
                for (int j = 0; j < 4; ++j)
                    acc[i][j] = __builtin_amdgcn_mfma_f32_16x16x32_bf16(a[i], bf[j], acc[i][j], 0, 0, 0);
        }

        float vv[4];
#pragma unroll
        for (int j = 0; j < 4; ++j) vv[j] = v1[b * 128 + wc * 64 + j * 16 + lr];

#pragma unroll
        for (int i = 0; i < 4; ++i) {
#pragma unroll
            for (int r = 0; r < 4; ++r) {
                float s = 0.f;
#pragma unroll
                for (int j = 0; j < 4; ++j) s += fmaxf(acc[i][j][r], 0.f) * vv[j];
                s += __shfl_xor(s, 1);
                s += __shfl_xor(s, 2);
                s += __shfl_xor(s, 4);
                s += __shfl_xor(s, 8);
                if (lr == 0) part[b][wc][i * 16 + g * 4 + r] = s;
            }
        }
    }
    __syncthreads();

    if (t < 256) {
        int b = t >> 6;
        int r = t & 63;
        int grow = base + r;
        if (grow < NN) z[grow * 4 + b] = part[b][0][r] + part[b][1][r];
    }
}

// ---- y[b,r] = reg_b[b] + sum_e val * z[col,b] : wave per row (ELL) ---------

__global__ void k_spmv(const int* __restrict__ deg, const uint2* __restrict__ epack,
                       const float* __restrict__ z, const float* __restrict__ regb,
                       float* __restrict__ y) {
    int wave = (blockIdx.x * 256 + threadIdx.x) >> 6;
    int lane = threadIdx.x & 63;
    if (wave >= NN) return;
    int d = deg[wave];
    int eg = lane >> 2;
    int b = lane & 3;
    int p0 = wave << 6;
    float acc = 0.f;
    for (int p = eg; p < d; p += 16) {
        uint2 ep = epack[p0 + p];
        acc += __uint_as_float(ep.y) * z[(((size_t)ep.x) << 2) + b];
    }
    acc += __shfl_xor(acc, 4);
    acc += __shfl_xor(acc, 8);
    acc += __shfl_xor(acc, 16);
    acc += __shfl_xor(acc, 32);
    if (lane < 4) y[lane * NN + wave] = acc + regb[lane];
}

// ---- launch ----------------------------------------------------------------

extern "C" void kernel_launch(void* const* d_in, const int* in_sizes, int n_in,
                              void* d_out, int out_size, void* d_ws, size_t ws_size,
                              hipStream_t stream) {
    const float* x    = (const float*)d_in[0];
    const int*   rows = (const int*)d_in[1];
    const int*   cols = (const int*)d_in[2];
    const float* vals = (const float*)d_in[3];
    const float* w0   = (const float*)d_in[4];
    const float* w1   = (const float*)d_in[5];
    const float* regw = (const float*)d_in[6];
    const float* regb = (const float*)d_in[7];
    float* y = (float*)d_out;

    char* ws = (char*)d_ws;
    int*   deg   = (int*)(ws + 0);                   //     81,920 B
    uint2* epack = (uint2*)(ws + 81920);             // 10,240,000 B (ELL 20000x64x8)
    u16*   xb    = (u16*)(ws + 10321920);            //  5,120,000 B
    u16*   w0t   = (u16*)(ws + 15441920);            //    131,072 B
    float* v1    = (float*)(ws + 15572992);          //      2,048 B
    float* z     = (float*)(ws + 15575040);          //    320,000 B
    // total ~15.9 MB

    hipMemsetAsync(deg, 0, NN * sizeof(int), stream);
    k_init<<<(NN * FF / 4 + 255) / 256, 256, 0, stream>>>(rows, cols, vals, deg, epack,
                                                          x, xb, w0, w1, regw, w0t, v1);
    k_spmm_gemm<<<(NN + 63) / 64, 512, 0, stream>>>(deg, epack, xb, w0t, v1, z);
    k_spmv<<<(NN * 64 + 255) / 256, 256, 0, stream>>>(deg, epack, z, regb, y);
}